// Round 1
// baseline (200.144 us; speedup 1.0000x reference)
//
#include <hip/hip_runtime.h>
#include <math.h>

#define NN   10000
#define DEG  16
#define SS   128
#define NRBF 20
#define GG   64
#define RC   10.0f
#define PI_F 3.14159265358979323846f
#define NB   8

__device__ __forceinline__ float silu_f(float x){
    return x / (1.0f + __expf(-x));
}

// ---------------------------------------------------------------------------
// Kernel 0: transpose weight matrices into workspace so k_update threads can
// stream PRIVATE contiguous float4 rows (16B/lane loads, L1-friendly).
//   uT  [c][s] = u_w   [s*SS + c]            (SS x SS)
//   vT  [c][s] = v_w   [s*SS + c]            (SS x SS)
//   w1T [c][i] = upd_w1[i*SS + c]            (SS x 2SS)
//   w2aT[c][j] = upd_w2[j*3SS +   SS + c]    (SS x SS)  (a_sv slice)
//   w2bT[c][j] = upd_w2[j*3SS + 2*SS + c]    (SS x SS)  (a_ss slice)
// 640 blocks x 128 threads; reads are strided (L2-absorbed, ~0.4MB total).
// ---------------------------------------------------------------------------
__global__ __launch_bounds__(128) void k_prep(
    const float* __restrict__ u_w, const float* __restrict__ v_w,
    const float* __restrict__ upd_w1, const float* __restrict__ upd_w2,
    float* __restrict__ uT, float* __restrict__ vT,
    float* __restrict__ w1T, float* __restrict__ w2aT, float* __restrict__ w2bT){
    int b = blockIdx.x;
    int t = threadIdx.x;
    if (b < 128){
        uT[b*SS + t] = u_w[t*SS + b];
    } else if (b < 256){
        int c = b - 128;
        vT[c*SS + t] = v_w[t*SS + c];
    } else if (b < 384){
        int c = b - 256;
        w1T[c*2*SS + t]      = upd_w1[t*SS + c];
        w1T[c*2*SS + SS + t] = upd_w1[(SS + t)*SS + c];
    } else if (b < 512){
        int c = b - 384;
        w2aT[c*SS + t] = upd_w2[t*3*SS + SS + c];
    } else {
        int c = b - 512;
        w2bT[c*SS + t] = upd_w2[t*3*SS + 2*SS + c];
    }
}

// ---------------------------------------------------------------------------
// Kernel 1a: h = silu(s0 @ phi_w1 + b1)  (s0 uniform). Also zeroes gs.
// ---------------------------------------------------------------------------
__global__ __launch_bounds__(256) void k_phi1(
    const float* __restrict__ emb0,
    const float* __restrict__ w1, const float* __restrict__ b1,
    float* __restrict__ phiH, float* __restrict__ gs){
    __shared__ float s0[SS];
    __shared__ float part[2][SS];
    int t = threadIdx.x;
    for (int i = t; i < GG*SS; i += 256) gs[i] = 0.0f;
    if (t < SS) s0[t] = 128.0f * emb0[t];
    __syncthreads();
    int c = t & 127, half = t >> 7;
    float acc = 0.0f;
    int s0i = half * 64;
    #pragma unroll 8
    for (int s = 0; s < 64; s++)
        acc = fmaf(s0[s0i + s], w1[(s0i + s)*SS + c], acc);
    part[half][c] = acc;
    __syncthreads();
    if (t < SS) phiH[t] = silu_f(b1[t] + part[0][t] + part[1][t]);
}

// ---------------------------------------------------------------------------
// Kernel 1b: phiW = h @ phi_w2 + b2.
// ---------------------------------------------------------------------------
__global__ __launch_bounds__(128) void k_phi2(
    const float* __restrict__ phiH,
    const float* __restrict__ w2, const float* __restrict__ b2,
    float* __restrict__ phiW){
    __shared__ float hL[SS];
    __shared__ float part[4][32];
    int t = threadIdx.x;
    hL[t] = phiH[t];
    __syncthreads();
    int c  = blockIdx.x*32 + (t & 31);
    int kk = t >> 5;
    float acc = 0.0f;
    int sbase = kk * 32;
    #pragma unroll 8
    for (int s = 0; s < 32; s++)
        acc = fmaf(hL[sbase + s], w2[(sbase + s)*3*SS + c], acc);
    part[kk][t & 31] = acc;
    __syncthreads();
    if (t < 32){
        int cc = blockIdx.x*32 + t;
        phiW[cc] = b2[cc] + part[0][t] + part[1][t] + part[2][t] + part[3][t];
    }
}

// ---------------------------------------------------------------------------
// Kernel 2: per-node edge processing (unchanged — not yet in the top-5).
// ---------------------------------------------------------------------------
__global__ __launch_bounds__(128) void k_edge(
    const float* __restrict__ evd, const float* __restrict__ elen,
    const int* __restrict__ node_from,
    const float* __restrict__ filt_w, const float* __restrict__ filt_b,
    const float* __restrict__ phiW,
    float* __restrict__ state, float* __restrict__ sv){
    __shared__ float rS[DEG];
    __shared__ float mcL[DEG];
    __shared__ float frL[DEG];
    __shared__ float eV[DEG][3];
    __shared__ float rbfL[DEG][NRBF];
    __shared__ float invD;
    int n = blockIdx.x;
    int t = threadIdx.x;

    if (t < DEG){
        int e = n*DEG + t;
        float x = evd[3*e+0], y = evd[3*e+1], z = evd[3*e+2];
        float r = sqrtf(x*x + y*y + z*z);
        float len  = elen[e];
        float mask = (fabsf(len) <= RC) ? 1.0f : 0.0f;
        float cut  = (r < RC) ? 0.5f*(cosf(PI_F*r*(1.0f/RC)) + 1.0f) : 0.0f;
        rS[t]  = fmaxf(r, 1e-12f);
        mcL[t] = mask * cut;
        frL[t] = mask * r * r;
        eV[t][0] = x; eV[t][1] = y; eV[t][2] = z;
    }
    __syncthreads();
    for (int idx = t; idx < DEG*NRBF; idx += 128){
        int e = idx / NRBF, k = idx % NRBF;
        float rs = rS[e];
        rbfL[e][k] = sinf((float)(k+1) * (PI_F/RC) * rs) / rs;
    }
    if (t == 0){
        float s = 0.0f;
        for (int e = 0; e < DEG; e++) s += frL[e];
        float fbn = sqrtf(s);
        invD = (fbn > 0.0f) ? 1.0f/fbn : 1.0f;
    }
    __syncthreads();

    int gc1 = SS + t;
    int gc2 = 2*SS + t;
    float fw1[NRBF], fw2[NRBF];
    #pragma unroll
    for (int k = 0; k < NRBF; k++){
        fw1[k] = filt_w[k*(3*SS) + gc1];
        fw2[k] = filt_w[k*(3*SS) + gc2];
    }
    float fb1 = filt_b[gc1], fb2 = filt_b[gc2];
    float ph1 = phiW[gc1],   ph2 = phiW[gc2];
    float iD  = invD;
    int   s3  = t % 3;

    float acc1 = 0.0f, acc2 = 0.0f;
    for (int e = 0; e < DEG; e++){
        float mc = mcL[e];
        if (mc == 0.0f) continue;
        const float4* rv = (const float4*)(&rbfL[e][0]);
        float4 r0 = rv[0], r1 = rv[1], r2 = rv[2], r3 = rv[3], r4 = rv[4];
        float rr[20] = {r0.x,r0.y,r0.z,r0.w, r1.x,r1.y,r1.z,r1.w,
                        r2.x,r2.y,r2.z,r2.w, r3.x,r3.y,r3.z,r3.w,
                        r4.x,r4.y,r4.z,r4.w};
        float w1 = fb1, w2 = fb2;
        #pragma unroll
        for (int k = 0; k < NRBF; k++){
            w1 = fmaf(rr[k], fw1[k], w1);
            w2 = fmaf(rr[k], fw2[k], w2);
        }
        acc1 = fmaf(ph1*mc, w1, acc1);
        acc2 = fmaf(ph2*mc*eV[e][s3]*iD, w2, acc2);
    }
    int nf = node_from[n*DEG];
    state[nf*SS + t] = acc1;
    sv[nf*SS + t]    = acc2;
}

// ---------------------------------------------------------------------------
// Kernel 3: per-node update, NB=8 nodes per 128-thread block.
// NEW: all weight operands come from TRANSPOSED copies, so thread t streams
// contiguous private float4 rows (uT/vT: 512B, w1T: 1KB, w2aT/w2bT: 512B).
// 4x fewer load instructions, 32 FMAs per 16B load, L1-resident streams.
// ---------------------------------------------------------------------------
__global__ __launch_bounds__(128) void k_update(
    const float* __restrict__ state, const float* __restrict__ sv,
    const float* __restrict__ uT, const float* __restrict__ vT,
    const float* __restrict__ w1T, const float* __restrict__ upd_b1,
    const float* __restrict__ w2aT, const float* __restrict__ w2bT,
    const float* __restrict__ upd_b2,
    const int* __restrict__ ngi, float* __restrict__ gs){
    __shared__ float svT[SS][NB];     // [s][b]
    __shared__ float xT[2*SS][NB];    // [i][b]: i<SS -> Vnorm, i>=SS -> state
    __shared__ float h2T[SS][NB];
    __shared__ float red[2][NB];
    __shared__ float dL[NB];
    int t  = threadIdx.x;
    int n0 = blockIdx.x * NB;

    for (int idx = t; idx < NB*SS; idx += 128){
        int b = idx >> 7, s = idx & (SS-1);
        svT[s][b]     = sv[(n0+b)*SS + s];
        xT[SS+s][b]   = state[(n0+b)*SS + s];
    }
    __syncthreads();

    // ---- loop1: u = sv@u_w, v = sv@v_w (channel t), float4 weight streams
    float accU[NB], accV[NB];
    #pragma unroll
    for (int b = 0; b < NB; b++){ accU[b]=0.f; accV[b]=0.f; }
    const float4* up = (const float4*)(uT + t*SS);
    const float4* vp = (const float4*)(vT + t*SS);
    #pragma unroll 4
    for (int s4 = 0; s4 < SS/4; s4++){
        float4 u4 = up[s4], v4 = vp[s4];
        float uu[4] = {u4.x,u4.y,u4.z,u4.w};
        float vv[4] = {v4.x,v4.y,v4.z,v4.w};
        #pragma unroll
        for (int q = 0; q < 4; q++){
            const float4* sp = (const float4*)(&svT[4*s4+q][0]);
            float4 s03 = sp[0], s47 = sp[1];
            float svv[NB] = {s03.x,s03.y,s03.z,s03.w,s47.x,s47.y,s47.z,s47.w};
            #pragma unroll
            for (int b = 0; b < NB; b++){
                accU[b] = fmaf(svv[b], uu[q], accU[b]);
                accV[b] = fmaf(svv[b], vv[q], accV[b]);
            }
        }
    }

    int lane = t & 63, wid = t >> 6;
    #pragma unroll
    for (int b = 0; b < NB; b++){
        float p = accU[b]*accV[b];
        for (int off = 32; off; off >>= 1) p += __shfl_down(p, off);
        if (lane == 0) red[wid][b] = p;
    }
    {   // Vnorm = sqrt(3 v^2)
        float4 q0, q1;
        q0.x = sqrtf(3.f*accV[0]*accV[0]); q0.y = sqrtf(3.f*accV[1]*accV[1]);
        q0.z = sqrtf(3.f*accV[2]*accV[2]); q0.w = sqrtf(3.f*accV[3]*accV[3]);
        q1.x = sqrtf(3.f*accV[4]*accV[4]); q1.y = sqrtf(3.f*accV[5]*accV[5]);
        q1.z = sqrtf(3.f*accV[6]*accV[6]); q1.w = sqrtf(3.f*accV[7]*accV[7]);
        ((float4*)(&xT[t][0]))[0] = q0;
        ((float4*)(&xT[t][0]))[1] = q1;
    }
    __syncthreads();
    if (t < NB) dL[t] = red[0][t] + red[1][t];

    // ---- loop2: h = silu(x @ upd_w1 + b1), w1T row = 1KB private stream
    float accH[NB];
    #pragma unroll
    for (int b = 0; b < NB; b++) accH[b] = 0.f;
    const float4* w1p = (const float4*)(w1T + t*(2*SS));
    #pragma unroll 4
    for (int i4 = 0; i4 < (2*SS)/4; i4++){
        float4 w4 = w1p[i4];
        float ww[4] = {w4.x,w4.y,w4.z,w4.w};
        #pragma unroll
        for (int q = 0; q < 4; q++){
            const float4* xp = (const float4*)(&xT[4*i4+q][0]);
            float4 x03 = xp[0], x47 = xp[1];
            float xv[NB] = {x03.x,x03.y,x03.z,x03.w,x47.x,x47.y,x47.z,x47.w};
            #pragma unroll
            for (int b = 0; b < NB; b++) accH[b] = fmaf(xv[b], ww[q], accH[b]);
        }
    }
    float b1v = upd_b1[t];
    {
        float4 q0, q1;
        q0.x = silu_f(accH[0]+b1v); q0.y = silu_f(accH[1]+b1v);
        q0.z = silu_f(accH[2]+b1v); q0.w = silu_f(accH[3]+b1v);
        q1.x = silu_f(accH[4]+b1v); q1.y = silu_f(accH[5]+b1v);
        q1.z = silu_f(accH[6]+b1v); q1.w = silu_f(accH[7]+b1v);
        ((float4*)(&h2T[t][0]))[0] = q0;
        ((float4*)(&h2T[t][0]))[1] = q1;
    }
    __syncthreads();

    // ---- loop3: a_sv, a_ss channels via w2aT/w2bT private streams
    float a1[NB], a2[NB];
    #pragma unroll
    for (int b = 0; b < NB; b++){ a1[b]=0.f; a2[b]=0.f; }
    const float4* ap = (const float4*)(w2aT + t*SS);
    const float4* bp = (const float4*)(w2bT + t*SS);
    #pragma unroll 4
    for (int j4 = 0; j4 < SS/4; j4++){
        float4 a4 = ap[j4], b4 = bp[j4];
        float wa[4] = {a4.x,a4.y,a4.z,a4.w};
        float wb[4] = {b4.x,b4.y,b4.z,b4.w};
        #pragma unroll
        for (int q = 0; q < 4; q++){
            const float4* hp = (const float4*)(&h2T[4*j4+q][0]);
            float4 h03 = hp[0], h47 = hp[1];
            float hv[NB] = {h03.x,h03.y,h03.z,h03.w,h47.x,h47.y,h47.z,h47.w};
            #pragma unroll
            for (int b = 0; b < NB; b++){
                a1[b] = fmaf(hv[b], wa[q], a1[b]);
                a2[b] = fmaf(hv[b], wb[q], a2[b]);
            }
        }
    }
    float bsv = upd_b2[SS+t], bss = upd_b2[2*SS+t];
    #pragma unroll
    for (int b = 0; b < NB; b++){
        float ns = (a2[b] + bss) + 3.0f*dL[b]*(a1[b] + bsv);
        int g = ngi[n0+b];
        atomicAdd(&gs[g*SS + t], ns);
    }
}

// ---------------------------------------------------------------------------
// Kernel 4: readout per graph
// ---------------------------------------------------------------------------
__global__ __launch_bounds__(128) void k_out(
    const float* __restrict__ gs,
    const float* __restrict__ w1, const float* __restrict__ b1,
    const float* __restrict__ w2, const float* __restrict__ b2,
    float* __restrict__ out){
    __shared__ float gsL[SS];
    __shared__ float red[2];
    int g = blockIdx.x, t = threadIdx.x;
    gsL[t] = gs[g*SS + t];
    __syncthreads();
    float acc = b1[t];
    #pragma unroll 4
    for (int s = 0; s < SS; s++) acc = fmaf(gsL[s], w1[s*SS + t], acc);
    float p = silu_f(acc) * w2[t];
    for (int off = 32; off; off >>= 1) p += __shfl_down(p, off);
    if ((t & 63) == 0) red[t >> 6] = p;
    __syncthreads();
    if (t == 0) out[g] = red[0] + red[1] + b2[0];
}

extern "C" void kernel_launch(void* const* d_in, const int* in_sizes, int n_in,
                              void* d_out, int out_size, void* d_ws, size_t ws_size,
                              hipStream_t stream) {
    const float* evd     = (const float*)d_in[0];
    const float* elen    = (const float*)d_in[1];
    const int*   nfrom   = (const int*)  d_in[2];
    const int*   ngi     = (const int*)  d_in[3];
    // d_in[4] = num_graphs (device scalar) — G=64 fixed by setup
    const float* emb0    = (const float*)d_in[5];
    const float* phi_w1  = (const float*)d_in[6];
    const float* phi_b1  = (const float*)d_in[7];
    const float* phi_w2  = (const float*)d_in[8];
    const float* phi_b2  = (const float*)d_in[9];
    const float* filt_w  = (const float*)d_in[10];
    const float* filt_b  = (const float*)d_in[11];
    const float* u_w     = (const float*)d_in[12];
    const float* v_w     = (const float*)d_in[13];
    const float* upd_w1  = (const float*)d_in[14];
    const float* upd_b1  = (const float*)d_in[15];
    const float* upd_w2  = (const float*)d_in[16];
    const float* upd_b2  = (const float*)d_in[17];
    const float* out_w1  = (const float*)d_in[18];
    const float* out_b1  = (const float*)d_in[19];
    const float* out_w2  = (const float*)d_in[20];
    const float* out_b2  = (const float*)d_in[21];

    float* ws    = (float*)d_ws;
    float* phiW  = ws;                       // 384 (pad to 512)
    float* state = ws + 512;                 // N*S
    float* sv    = state + NN*SS;            // N*S
    float* gs    = sv + NN*SS;               // G*S
    float* phiH  = gs + GG*SS;               // 128
    float* uT    = phiH + 128;               // S*S
    float* vT    = uT + SS*SS;               // S*S
    float* w1T   = vT + SS*SS;               // 2S*S
    float* w2aT  = w1T + 2*SS*SS;            // S*S
    float* w2bT  = w2aT + SS*SS;             // S*S

    k_prep<<<640, 128, 0, stream>>>(u_w, v_w, upd_w1, upd_w2,
                                    uT, vT, w1T, w2aT, w2bT);
    k_phi1<<<1, 256, 0, stream>>>(emb0, phi_w1, phi_b1, phiH, gs);
    k_phi2<<<12, 128, 0, stream>>>(phiH, phi_w2, phi_b2, phiW);
    k_edge<<<NN, 128, 0, stream>>>(evd, elen, nfrom, filt_w, filt_b, phiW, state, sv);
    k_update<<<NN/NB, 128, 0, stream>>>(state, sv, uT, vT,
                                        w1T, upd_b1, w2aT, w2bT, upd_b2, ngi, gs);
    k_out<<<GG, 128, 0, stream>>>(gs, out_w1, out_b1, out_w2, out_b2, (float*)d_out);
}

// Round 3
// 199.774 us; speedup vs baseline: 1.0019x; 1.0019x over previous
//
#include <hip/hip_runtime.h>
#include <math.h>

#define NN   10000
#define DEG  16
#define SS   128
#define NRBF 20
#define GG   64
#define RC   10.0f
#define PI_F 3.14159265358979323846f
#define NB   8
#define TS   16

__device__ __forceinline__ float silu_f(float x){
    return x / (1.0f + __expf(-x));
}

// ---------------------------------------------------------------------------
// Kernel 1a: h = silu(s0 @ phi_w1 + b1)  (s0 uniform). Also zeroes gs.
// ---------------------------------------------------------------------------
__global__ __launch_bounds__(256) void k_phi1(
    const float* __restrict__ emb0,
    const float* __restrict__ w1, const float* __restrict__ b1,
    float* __restrict__ phiH, float* __restrict__ gs){
    __shared__ float s0[SS];
    __shared__ float part[2][SS];
    int t = threadIdx.x;
    for (int i = t; i < GG*SS; i += 256) gs[i] = 0.0f;
    if (t < SS) s0[t] = 128.0f * emb0[t];
    __syncthreads();
    int c = t & 127, half = t >> 7;
    float acc = 0.0f;
    int s0i = half * 64;
    #pragma unroll 8
    for (int s = 0; s < 64; s++)
        acc = fmaf(s0[s0i + s], w1[(s0i + s)*SS + c], acc);
    part[half][c] = acc;
    __syncthreads();
    if (t < SS) phiH[t] = silu_f(b1[t] + part[0][t] + part[1][t]);
}

// ---------------------------------------------------------------------------
// Kernel 1b: phiW = h @ phi_w2 + b2.
// ---------------------------------------------------------------------------
__global__ __launch_bounds__(128) void k_phi2(
    const float* __restrict__ phiH,
    const float* __restrict__ w2, const float* __restrict__ b2,
    float* __restrict__ phiW){
    __shared__ float hL[SS];
    __shared__ float part[4][32];
    int t = threadIdx.x;
    hL[t] = phiH[t];
    __syncthreads();
    int c  = blockIdx.x*32 + (t & 31);
    int kk = t >> 5;
    float acc = 0.0f;
    int sbase = kk * 32;
    #pragma unroll 8
    for (int s = 0; s < 32; s++)
        acc = fmaf(hL[sbase + s], w2[(sbase + s)*3*SS + c], acc);
    part[kk][t & 31] = acc;
    __syncthreads();
    if (t < 32){
        int cc = blockIdx.x*32 + t;
        phiW[cc] = b2[cc] + part[0][t] + part[1][t] + part[2][t] + part[3][t];
    }
}

// ---------------------------------------------------------------------------
// Kernel 2: per-node edge processing (unchanged).
// ---------------------------------------------------------------------------
__global__ __launch_bounds__(128) void k_edge(
    const float* __restrict__ evd, const float* __restrict__ elen,
    const int* __restrict__ node_from,
    const float* __restrict__ filt_w, const float* __restrict__ filt_b,
    const float* __restrict__ phiW,
    float* __restrict__ state, float* __restrict__ sv){
    __shared__ float rS[DEG];
    __shared__ float mcL[DEG];
    __shared__ float frL[DEG];
    __shared__ float eV[DEG][3];
    __shared__ float rbfL[DEG][NRBF];
    __shared__ float invD;
    int n = blockIdx.x;
    int t = threadIdx.x;

    if (t < DEG){
        int e = n*DEG + t;
        float x = evd[3*e+0], y = evd[3*e+1], z = evd[3*e+2];
        float r = sqrtf(x*x + y*y + z*z);
        float len  = elen[e];
        float mask = (fabsf(len) <= RC) ? 1.0f : 0.0f;
        float cut  = (r < RC) ? 0.5f*(cosf(PI_F*r*(1.0f/RC)) + 1.0f) : 0.0f;
        rS[t]  = fmaxf(r, 1e-12f);
        mcL[t] = mask * cut;
        frL[t] = mask * r * r;
        eV[t][0] = x; eV[t][1] = y; eV[t][2] = z;
    }
    __syncthreads();
    for (int idx = t; idx < DEG*NRBF; idx += 128){
        int e = idx / NRBF, k = idx % NRBF;
        float rs = rS[e];
        rbfL[e][k] = sinf((float)(k+1) * (PI_F/RC) * rs) / rs;
    }
    if (t == 0){
        float s = 0.0f;
        for (int e = 0; e < DEG; e++) s += frL[e];
        float fbn = sqrtf(s);
        invD = (fbn > 0.0f) ? 1.0f/fbn : 1.0f;
    }
    __syncthreads();

    int gc1 = SS + t;
    int gc2 = 2*SS + t;
    float fw1[NRBF], fw2[NRBF];
    #pragma unroll
    for (int k = 0; k < NRBF; k++){
        fw1[k] = filt_w[k*(3*SS) + gc1];
        fw2[k] = filt_w[k*(3*SS) + gc2];
    }
    float fb1 = filt_b[gc1], fb2 = filt_b[gc2];
    float ph1 = phiW[gc1],   ph2 = phiW[gc2];
    float iD  = invD;
    int   s3  = t % 3;

    float acc1 = 0.0f, acc2 = 0.0f;
    for (int e = 0; e < DEG; e++){
        float mc = mcL[e];
        if (mc == 0.0f) continue;
        const float4* rv = (const float4*)(&rbfL[e][0]);
        float4 r0 = rv[0], r1 = rv[1], r2 = rv[2], r3 = rv[3], r4 = rv[4];
        float rr[20] = {r0.x,r0.y,r0.z,r0.w, r1.x,r1.y,r1.z,r1.w,
                        r2.x,r2.y,r2.z,r2.w, r3.x,r3.y,r3.z,r3.w,
                        r4.x,r4.y,r4.z,r4.w};
        float w1 = fb1, w2 = fb2;
        #pragma unroll
        for (int k = 0; k < NRBF; k++){
            w1 = fmaf(rr[k], fw1[k], w1);
            w2 = fmaf(rr[k], fw2[k], w2);
        }
        acc1 = fmaf(ph1*mc, w1, acc1);
        acc2 = fmaf(ph2*mc*eV[e][s3]*iD, w2, acc2);
    }
    int nf = node_from[n*DEG];
    state[nf*SS + t] = acc1;
    sv[nf*SS + t]    = acc2;
}

// ---------------------------------------------------------------------------
// Kernel 3: per-node update, NB=8 nodes / 128-thread block.
// Weights flow: coalesced float4 GLOBAL loads (register prefetch of tile k+1
// issued before compute of tile k) -> LDS tile -> scalar LDS reads in the FMA
// loop (bank = t%32 -> free 2-way). Activations broadcast from LDS as float4.
// ---------------------------------------------------------------------------
__global__ __launch_bounds__(128) void k_update(
    const float* __restrict__ state, const float* __restrict__ sv,
    const float* __restrict__ u_w, const float* __restrict__ v_w,
    const float* __restrict__ upd_w1, const float* __restrict__ upd_b1,
    const float* __restrict__ upd_w2, const float* __restrict__ upd_b2,
    const int* __restrict__ ngi, float* __restrict__ gs){
    __shared__ float wA[TS*SS];       // 8KB weight tile A
    __shared__ float wB[TS*SS];       // 8KB weight tile B
    __shared__ float svT[SS][NB];     // [s][b]
    __shared__ float xT[2*SS][NB];    // [i][b]: i<SS -> Vnorm, i>=SS -> state
    __shared__ float h2T[SS][NB];
    __shared__ float red[2][NB];
    __shared__ float dL[NB];
    int t  = threadIdx.x;
    int n0 = blockIdx.x * NB;

    for (int idx = t; idx < NB*SS; idx += 128){
        int b = idx >> 7, s = idx & (SS-1);
        svT[s][b]   = sv[(n0+b)*SS + s];
        xT[SS+s][b] = state[(n0+b)*SS + s];
    }

    float4* wA4 = (float4*)wA;
    float4* wB4 = (float4*)wB;

    // ---- loop1: u = sv@u_w, v = sv@v_w. 8 tiles of 16 K-rows, both matrices.
    const float4* ug = (const float4*)u_w;
    const float4* vg = (const float4*)v_w;
    float4 pa0 = ug[t], pa1 = ug[t+128], pa2 = ug[t+256], pa3 = ug[t+384];
    float4 pb0 = vg[t], pb1 = vg[t+128], pb2 = vg[t+256], pb3 = vg[t+384];

    float accU[NB], accV[NB];
    #pragma unroll
    for (int b = 0; b < NB; b++){ accU[b]=0.f; accV[b]=0.f; }

    for (int s0 = 0; s0 < SS; s0 += TS){
        wA4[t] = pa0; wA4[t+128] = pa1; wA4[t+256] = pa2; wA4[t+384] = pa3;
        wB4[t] = pb0; wB4[t+128] = pb1; wB4[t+256] = pb2; wB4[t+384] = pb3;
        if (s0 + TS < SS){
            int base = (s0 + TS)*(SS/4);
            pa0 = ug[base+t]; pa1 = ug[base+t+128];
            pa2 = ug[base+t+256]; pa3 = ug[base+t+384];
            pb0 = vg[base+t]; pb1 = vg[base+t+128];
            pb2 = vg[base+t+256]; pb3 = vg[base+t+384];
        }
        __syncthreads();
        #pragma unroll
        for (int s = 0; s < TS; s++){
            float wu = wA[s*SS + t];
            float wv = wB[s*SS + t];
            const float4* sp = (const float4*)(&svT[s0+s][0]);
            float4 s03 = sp[0], s47 = sp[1];
            float svv[NB] = {s03.x,s03.y,s03.z,s03.w,s47.x,s47.y,s47.z,s47.w};
            #pragma unroll
            for (int b = 0; b < NB; b++){
                accU[b] = fmaf(svv[b], wu, accU[b]);
                accV[b] = fmaf(svv[b], wv, accV[b]);
            }
        }
        __syncthreads();
    }

    int lane = t & 63, wid = t >> 6;
    #pragma unroll
    for (int b = 0; b < NB; b++){
        float p = accU[b]*accV[b];
        for (int off = 32; off; off >>= 1) p += __shfl_down(p, off);
        if (lane == 0) red[wid][b] = p;
    }
    {   // Vnorm = sqrt(3 v^2)
        float4 q0, q1;
        q0.x = sqrtf(3.f*accV[0]*accV[0]); q0.y = sqrtf(3.f*accV[1]*accV[1]);
        q0.z = sqrtf(3.f*accV[2]*accV[2]); q0.w = sqrtf(3.f*accV[3]*accV[3]);
        q1.x = sqrtf(3.f*accV[4]*accV[4]); q1.y = sqrtf(3.f*accV[5]*accV[5]);
        q1.z = sqrtf(3.f*accV[6]*accV[6]); q1.w = sqrtf(3.f*accV[7]*accV[7]);
        ((float4*)(&xT[t][0]))[0] = q0;
        ((float4*)(&xT[t][0]))[1] = q1;
    }
    __syncthreads();
    if (t < NB) dL[t] = red[0][t] + red[1][t];

    // ---- loop2: h = silu(x @ upd_w1 + b1). K=256; 8 iters of 32 rows
    // (16 rows in wA, 16 in wB).
    const float4* w1g = (const float4*)upd_w1;
    {
        pa0 = w1g[t];     pa1 = w1g[t+128]; pa2 = w1g[t+256]; pa3 = w1g[t+384];
        pb0 = w1g[t+512]; pb1 = w1g[t+640]; pb2 = w1g[t+768]; pb3 = w1g[t+896];
    }
    float accH[NB];
    #pragma unroll
    for (int b = 0; b < NB; b++) accH[b] = 0.f;

    for (int i0 = 0; i0 < 2*SS; i0 += 2*TS){
        wA4[t] = pa0; wA4[t+128] = pa1; wA4[t+256] = pa2; wA4[t+384] = pa3;
        wB4[t] = pb0; wB4[t+128] = pb1; wB4[t+256] = pb2; wB4[t+384] = pb3;
        if (i0 + 2*TS < 2*SS){
            int base = (i0 + 2*TS)*(SS/4);
            pa0 = w1g[base+t];     pa1 = w1g[base+t+128];
            pa2 = w1g[base+t+256]; pa3 = w1g[base+t+384];
            pb0 = w1g[base+t+512]; pb1 = w1g[base+t+640];
            pb2 = w1g[base+t+768]; pb3 = w1g[base+t+896];
        }
        __syncthreads();
        #pragma unroll
        for (int s = 0; s < TS; s++){
            float w = wA[s*SS + t];
            const float4* xp = (const float4*)(&xT[i0+s][0]);
            float4 x03 = xp[0], x47 = xp[1];
            float xv[NB] = {x03.x,x03.y,x03.z,x03.w,x47.x,x47.y,x47.z,x47.w};
            #pragma unroll
            for (int b = 0; b < NB; b++) accH[b] = fmaf(xv[b], w, accH[b]);
        }
        #pragma unroll
        for (int s = 0; s < TS; s++){
            float w = wB[s*SS + t];
            const float4* xp = (const float4*)(&xT[i0+TS+s][0]);
            float4 x03 = xp[0], x47 = xp[1];
            float xv[NB] = {x03.x,x03.y,x03.z,x03.w,x47.x,x47.y,x47.z,x47.w};
            #pragma unroll
            for (int b = 0; b < NB; b++) accH[b] = fmaf(xv[b], w, accH[b]);
        }
        __syncthreads();
    }
    float b1v = upd_b1[t];
    {
        float4 q0, q1;
        q0.x = silu_f(accH[0]+b1v); q0.y = silu_f(accH[1]+b1v);
        q0.z = silu_f(accH[2]+b1v); q0.w = silu_f(accH[3]+b1v);
        q1.x = silu_f(accH[4]+b1v); q1.y = silu_f(accH[5]+b1v);
        q1.z = silu_f(accH[6]+b1v); q1.w = silu_f(accH[7]+b1v);
        ((float4*)(&h2T[t][0]))[0] = q0;
        ((float4*)(&h2T[t][0]))[1] = q1;
    }

    // ---- loop3: a_sv (cols SS..2SS) in wA, a_ss (2SS..3SS) in wB.
    // Row j of upd_w2 = 96 float4; slice A at f4 +32, slice B at f4 +64.
    const float4* w2g = (const float4*)upd_w2;
    int r0q = t >> 5,          c4 = t & 31;           // element i=0
    int r1q = (t+128) >> 5;                            // i=1
    int r2q = (t+256) >> 5;                            // i=2
    int r3q = (t+384) >> 5;                            // i=3
    {
        pa0 = w2g[r0q*96 + 32 + c4]; pa1 = w2g[r1q*96 + 32 + c4];
        pa2 = w2g[r2q*96 + 32 + c4]; pa3 = w2g[r3q*96 + 32 + c4];
        pb0 = w2g[r0q*96 + 64 + c4]; pb1 = w2g[r1q*96 + 64 + c4];
        pb2 = w2g[r2q*96 + 64 + c4]; pb3 = w2g[r3q*96 + 64 + c4];
    }
    float a1[NB], a2[NB];
    #pragma unroll
    for (int b = 0; b < NB; b++){ a1[b]=0.f; a2[b]=0.f; }

    for (int j0 = 0; j0 < SS; j0 += TS){
        wA4[t] = pa0; wA4[t+128] = pa1; wA4[t+256] = pa2; wA4[t+384] = pa3;
        wB4[t] = pb0; wB4[t+128] = pb1; wB4[t+256] = pb2; wB4[t+384] = pb3;
        if (j0 + TS < SS){
            int jb = j0 + TS;
            pa0 = w2g[(jb+r0q)*96 + 32 + c4]; pa1 = w2g[(jb+r1q)*96 + 32 + c4];
            pa2 = w2g[(jb+r2q)*96 + 32 + c4]; pa3 = w2g[(jb+r3q)*96 + 32 + c4];
            pb0 = w2g[(jb+r0q)*96 + 64 + c4]; pb1 = w2g[(jb+r1q)*96 + 64 + c4];
            pb2 = w2g[(jb+r2q)*96 + 64 + c4]; pb3 = w2g[(jb+r3q)*96 + 64 + c4];
        }
        __syncthreads();
        #pragma unroll
        for (int s = 0; s < TS; s++){
            float wa = wA[s*SS + t];
            float wb = wB[s*SS + t];
            const float4* hp = (const float4*)(&h2T[j0+s][0]);
            float4 h03 = hp[0], h47 = hp[1];
            float hv[NB] = {h03.x,h03.y,h03.z,h03.w,h47.x,h47.y,h47.z,h47.w};
            #pragma unroll
            for (int b = 0; b < NB; b++){
                a1[b] = fmaf(hv[b], wa, a1[b]);
                a2[b] = fmaf(hv[b], wb, a2[b]);
            }
        }
        __syncthreads();
    }

    float bsv = upd_b2[SS+t], bss = upd_b2[2*SS+t];
    #pragma unroll
    for (int b = 0; b < NB; b++){
        float ns = (a2[b] + bss) + 3.0f*dL[b]*(a1[b] + bsv);
        int g = ngi[n0+b];
        atomicAdd(&gs[g*SS + t], ns);
    }
}

// ---------------------------------------------------------------------------
// Kernel 4: readout per graph
// ---------------------------------------------------------------------------
__global__ __launch_bounds__(128) void k_out(
    const float* __restrict__ gs,
    const float* __restrict__ w1, const float* __restrict__ b1,
    const float* __restrict__ w2, const float* __restrict__ b2,
    float* __restrict__ out){
    __shared__ float gsL[SS];
    __shared__ float red[2];
    int g = blockIdx.x, t = threadIdx.x;
    gsL[t] = gs[g*SS + t];
    __syncthreads();
    float acc = b1[t];
    #pragma unroll 4
    for (int s = 0; s < SS; s++) acc = fmaf(gsL[s], w1[s*SS + t], acc);
    float p = silu_f(acc) * w2[t];
    for (int off = 32; off; off >>= 1) p += __shfl_down(p, off);
    if ((t & 63) == 0) red[t >> 6] = p;
    __syncthreads();
    if (t == 0) out[g] = red[0] + red[1] + b2[0];
}

extern "C" void kernel_launch(void* const* d_in, const int* in_sizes, int n_in,
                              void* d_out, int out_size, void* d_ws, size_t ws_size,
                              hipStream_t stream) {
    const float* evd     = (const float*)d_in[0];
    const float* elen    = (const float*)d_in[1];
    const int*   nfrom   = (const int*)  d_in[2];
    const int*   ngi     = (const int*)  d_in[3];
    // d_in[4] = num_graphs (device scalar) — G=64 fixed by setup
    const float* emb0    = (const float*)d_in[5];
    const float* phi_w1  = (const float*)d_in[6];
    const float* phi_b1  = (const float*)d_in[7];
    const float* phi_w2  = (const float*)d_in[8];
    const float* phi_b2  = (const float*)d_in[9];
    const float* filt_w  = (const float*)d_in[10];
    const float* filt_b  = (const float*)d_in[11];
    const float* u_w     = (const float*)d_in[12];
    const float* v_w     = (const float*)d_in[13];
    const float* upd_w1  = (const float*)d_in[14];
    const float* upd_b1  = (const float*)d_in[15];
    const float* upd_w2  = (const float*)d_in[16];
    const float* upd_b2  = (const float*)d_in[17];
    const float* out_w1  = (const float*)d_in[18];
    const float* out_b1  = (const float*)d_in[19];
    const float* out_w2  = (const float*)d_in[20];
    const float* out_b2  = (const float*)d_in[21];

    float* ws    = (float*)d_ws;
    float* phiW  = ws;                       // 384 (pad to 512)
    float* state = ws + 512;                 // N*S
    float* sv    = state + NN*SS;            // N*S
    float* gs    = sv + NN*SS;               // G*S
    float* phiH  = gs + GG*SS;               // 128

    k_phi1<<<1, 256, 0, stream>>>(emb0, phi_w1, phi_b1, phiH, gs);
    k_phi2<<<12, 128, 0, stream>>>(phiH, phi_w2, phi_b2, phiW);
    k_edge<<<NN, 128, 0, stream>>>(evd, elen, nfrom, filt_w, filt_b, phiW, state, sv);
    k_update<<<NN/NB, 128, 0, stream>>>(state, sv, u_w, v_w,
                                        upd_w1, upd_b1, upd_w2, upd_b2, ngi, gs);
    k_out<<<GG, 128, 0, stream>>>(gs, out_w1, out_b1, out_w2, out_b2, (float*)d_out);
}

// Round 4
// 180.793 us; speedup vs baseline: 1.1070x; 1.1050x over previous
//
#include <hip/hip_runtime.h>
#include <math.h>

#define NN   10000
#define DEG  16
#define SS   128
#define NRBF 20
#define GG   64
#define RC   10.0f
#define PI_F 3.14159265358979323846f
#define NB   4

__device__ __forceinline__ float silu_f(float x){
    return x / (1.0f + __expf(-x));
}

// ---------------------------------------------------------------------------
// Kernel 1a: h = silu(s0 @ phi_w1 + b1)  (s0 uniform). Also zeroes gs.
// ---------------------------------------------------------------------------
__global__ __launch_bounds__(256) void k_phi1(
    const float* __restrict__ emb0,
    const float* __restrict__ w1, const float* __restrict__ b1,
    float* __restrict__ phiH, float* __restrict__ gs){
    __shared__ float s0[SS];
    __shared__ float part[2][SS];
    int t = threadIdx.x;
    for (int i = t; i < GG*SS; i += 256) gs[i] = 0.0f;
    if (t < SS) s0[t] = 128.0f * emb0[t];
    __syncthreads();
    int c = t & 127, half = t >> 7;
    float acc = 0.0f;
    int s0i = half * 64;
    #pragma unroll 8
    for (int s = 0; s < 64; s++)
        acc = fmaf(s0[s0i + s], w1[(s0i + s)*SS + c], acc);
    part[half][c] = acc;
    __syncthreads();
    if (t < SS) phiH[t] = silu_f(b1[t] + part[0][t] + part[1][t]);
}

// ---------------------------------------------------------------------------
// Kernel 1b: phiW = h @ phi_w2 + b2.
// ---------------------------------------------------------------------------
__global__ __launch_bounds__(128) void k_phi2(
    const float* __restrict__ phiH,
    const float* __restrict__ w2, const float* __restrict__ b2,
    float* __restrict__ phiW){
    __shared__ float hL[SS];
    __shared__ float part[4][32];
    int t = threadIdx.x;
    hL[t] = phiH[t];
    __syncthreads();
    int c  = blockIdx.x*32 + (t & 31);
    int kk = t >> 5;
    float acc = 0.0f;
    int sbase = kk * 32;
    #pragma unroll 8
    for (int s = 0; s < 32; s++)
        acc = fmaf(hL[sbase + s], w2[(sbase + s)*3*SS + c], acc);
    part[kk][t & 31] = acc;
    __syncthreads();
    if (t < 32){
        int cc = blockIdx.x*32 + t;
        phiW[cc] = b2[cc] + part[0][t] + part[1][t] + part[2][t] + part[3][t];
    }
}

// ---------------------------------------------------------------------------
// Kernel 2: per-node edge processing (unchanged — round-0 proven).
// ---------------------------------------------------------------------------
__global__ __launch_bounds__(128) void k_edge(
    const float* __restrict__ evd, const float* __restrict__ elen,
    const int* __restrict__ node_from,
    const float* __restrict__ filt_w, const float* __restrict__ filt_b,
    const float* __restrict__ phiW,
    float* __restrict__ state, float* __restrict__ sv){
    __shared__ float rS[DEG];
    __shared__ float mcL[DEG];
    __shared__ float frL[DEG];
    __shared__ float eV[DEG][3];
    __shared__ float rbfL[DEG][NRBF];
    __shared__ float invD;
    int n = blockIdx.x;
    int t = threadIdx.x;

    if (t < DEG){
        int e = n*DEG + t;
        float x = evd[3*e+0], y = evd[3*e+1], z = evd[3*e+2];
        float r = sqrtf(x*x + y*y + z*z);
        float len  = elen[e];
        float mask = (fabsf(len) <= RC) ? 1.0f : 0.0f;
        float cut  = (r < RC) ? 0.5f*(cosf(PI_F*r*(1.0f/RC)) + 1.0f) : 0.0f;
        rS[t]  = fmaxf(r, 1e-12f);
        mcL[t] = mask * cut;
        frL[t] = mask * r * r;
        eV[t][0] = x; eV[t][1] = y; eV[t][2] = z;
    }
    __syncthreads();
    for (int idx = t; idx < DEG*NRBF; idx += 128){
        int e = idx / NRBF, k = idx % NRBF;
        float rs = rS[e];
        rbfL[e][k] = sinf((float)(k+1) * (PI_F/RC) * rs) / rs;
    }
    if (t == 0){
        float s = 0.0f;
        for (int e = 0; e < DEG; e++) s += frL[e];
        float fbn = sqrtf(s);
        invD = (fbn > 0.0f) ? 1.0f/fbn : 1.0f;
    }
    __syncthreads();

    int gc1 = SS + t;
    int gc2 = 2*SS + t;
    float fw1[NRBF], fw2[NRBF];
    #pragma unroll
    for (int k = 0; k < NRBF; k++){
        fw1[k] = filt_w[k*(3*SS) + gc1];
        fw2[k] = filt_w[k*(3*SS) + gc2];
    }
    float fb1 = filt_b[gc1], fb2 = filt_b[gc2];
    float ph1 = phiW[gc1],   ph2 = phiW[gc2];
    float iD  = invD;
    int   s3  = t % 3;

    float acc1 = 0.0f, acc2 = 0.0f;
    for (int e = 0; e < DEG; e++){
        float mc = mcL[e];
        if (mc == 0.0f) continue;
        const float4* rv = (const float4*)(&rbfL[e][0]);
        float4 r0 = rv[0], r1 = rv[1], r2 = rv[2], r3 = rv[3], r4 = rv[4];
        float rr[20] = {r0.x,r0.y,r0.z,r0.w, r1.x,r1.y,r1.z,r1.w,
                        r2.x,r2.y,r2.z,r2.w, r3.x,r3.y,r3.z,r3.w,
                        r4.x,r4.y,r4.z,r4.w};
        float w1 = fb1, w2 = fb2;
        #pragma unroll
        for (int k = 0; k < NRBF; k++){
            w1 = fmaf(rr[k], fw1[k], w1);
            w2 = fmaf(rr[k], fw2[k], w2);
        }
        acc1 = fmaf(ph1*mc, w1, acc1);
        acc2 = fmaf(ph2*mc*eV[e][s3]*iD, w2, acc2);
    }
    int nf = node_from[n*DEG];
    state[nf*SS + t] = acc1;
    sv[nf*SS + t]    = acc2;
}

// ---------------------------------------------------------------------------
// Kernel 3: per-node update. ROUND-0 inner loop (proven fastest weight path:
// coalesced 4B weight loads, LDS float4 activation broadcasts) with NB 8->4:
// grid 1250 -> 2500 blocks => ~19.5 waves/CU ceiling (2.7x round-0's 7).
// Diagnosis across rounds 0/1/3: dur invariant to weight-delivery scheme,
// VALUBusy pinned at ~25% => wave-starved latency bound. Add waves.
// ---------------------------------------------------------------------------
__global__ __launch_bounds__(128) void k_update(
    const float* __restrict__ state, const float* __restrict__ sv,
    const float* __restrict__ u_w, const float* __restrict__ v_w,
    const float* __restrict__ upd_w1, const float* __restrict__ upd_b1,
    const float* __restrict__ upd_w2, const float* __restrict__ upd_b2,
    const int* __restrict__ ngi, float* __restrict__ gs){
    __shared__ __align__(16) float svT[SS][NB];     // [s][b]
    __shared__ __align__(16) float xT[2*SS][NB];    // [i][b]: i<SS Vnorm, i>=SS state
    __shared__ __align__(16) float h2T[SS][NB];
    __shared__ float red[2][NB];
    __shared__ float dL[NB];
    int t  = threadIdx.x;
    int n0 = blockIdx.x * NB;

    for (int idx = t; idx < NB*SS; idx += 128){
        int b = idx >> 7, s = idx & (SS-1);
        svT[s][b]     = sv[(n0+b)*SS + s];
        xT[SS+s][b]   = state[(n0+b)*SS + s];
    }
    __syncthreads();

    // ---- loop1: U = sv@u_w, V = sv@v_w for channel t, NB nodes
    float accU[NB], accV[NB];
    #pragma unroll
    for (int b = 0; b < NB; b++){ accU[b]=0.f; accV[b]=0.f; }
    for (int s = 0; s < SS; s++){
        float wu = u_w[s*SS + t];
        float wv = v_w[s*SS + t];
        float4 s03 = *((const float4*)(&svT[s][0]));
        float svv[NB] = {s03.x,s03.y,s03.z,s03.w};
        #pragma unroll
        for (int b = 0; b < NB; b++){
            accU[b] = fmaf(svv[b], wu, accU[b]);
            accV[b] = fmaf(svv[b], wv, accV[b]);
        }
    }

    int lane = t & 63, wid = t >> 6;
    #pragma unroll
    for (int b = 0; b < NB; b++){
        float p = accU[b]*accV[b];
        for (int off = 32; off; off >>= 1) p += __shfl_down(p, off);
        if (lane == 0) red[wid][b] = p;
    }
    {   // Vnorm = sqrt(V0^2+V1^2+V2^2) with V0=V1=V2 -> sqrt(3 v^2)
        float4 q0;
        q0.x = sqrtf(3.f*accV[0]*accV[0]); q0.y = sqrtf(3.f*accV[1]*accV[1]);
        q0.z = sqrtf(3.f*accV[2]*accV[2]); q0.w = sqrtf(3.f*accV[3]*accV[3]);
        ((float4*)(&xT[t][0]))[0] = q0;
    }
    __syncthreads();
    if (t < NB) dL[t] = red[0][t] + red[1][t];

    // ---- loop2: h = silu(x @ upd_w1 + b1), x = [Vnorm, state] (2S inputs)
    float accH[NB];
    #pragma unroll
    for (int b = 0; b < NB; b++) accH[b] = 0.f;
    for (int i = 0; i < 2*SS; i++){
        float w = upd_w1[i*SS + t];
        float4 x03 = *((const float4*)(&xT[i][0]));
        float xv[NB] = {x03.x,x03.y,x03.z,x03.w};
        #pragma unroll
        for (int b = 0; b < NB; b++) accH[b] = fmaf(xv[b], w, accH[b]);
    }
    float b1v = upd_b1[t];
    {
        float4 q0;
        q0.x = silu_f(accH[0]+b1v); q0.y = silu_f(accH[1]+b1v);
        q0.z = silu_f(accH[2]+b1v); q0.w = silu_f(accH[3]+b1v);
        ((float4*)(&h2T[t][0]))[0] = q0;
    }
    __syncthreads();

    // ---- loop3: a_sv, a_ss channels of h @ upd_w2
    float a1[NB], a2[NB];
    #pragma unroll
    for (int b = 0; b < NB; b++){ a1[b]=0.f; a2[b]=0.f; }
    for (int j = 0; j < SS; j++){
        float w1 = upd_w2[j*3*SS + SS   + t];   // a_sv channel
        float w2 = upd_w2[j*3*SS + 2*SS + t];   // a_ss channel
        float4 h03 = *((const float4*)(&h2T[j][0]));
        float hv[NB] = {h03.x,h03.y,h03.z,h03.w};
        #pragma unroll
        for (int b = 0; b < NB; b++){
            a1[b] = fmaf(hv[b], w1, a1[b]);
            a2[b] = fmaf(hv[b], w2, a2[b]);
        }
    }
    float bsv = upd_b2[SS+t], bss = upd_b2[2*SS+t];
    #pragma unroll
    for (int b = 0; b < NB; b++){
        float ns = (a2[b] + bss) + 3.0f*dL[b]*(a1[b] + bsv);
        int g = ngi[n0+b];
        atomicAdd(&gs[g*SS + t], ns);
    }
}

// ---------------------------------------------------------------------------
// Kernel 4: readout per graph
// ---------------------------------------------------------------------------
__global__ __launch_bounds__(128) void k_out(
    const float* __restrict__ gs,
    const float* __restrict__ w1, const float* __restrict__ b1,
    const float* __restrict__ w2, const float* __restrict__ b2,
    float* __restrict__ out){
    __shared__ float gsL[SS];
    __shared__ float red[2];
    int g = blockIdx.x, t = threadIdx.x;
    gsL[t] = gs[g*SS + t];
    __syncthreads();
    float acc = b1[t];
    #pragma unroll 4
    for (int s = 0; s < SS; s++) acc = fmaf(gsL[s], w1[s*SS + t], acc);
    float p = silu_f(acc) * w2[t];
    for (int off = 32; off; off >>= 1) p += __shfl_down(p, off);
    if ((t & 63) == 0) red[t >> 6] = p;
    __syncthreads();
    if (t == 0) out[g] = red[0] + red[1] + b2[0];
}

extern "C" void kernel_launch(void* const* d_in, const int* in_sizes, int n_in,
                              void* d_out, int out_size, void* d_ws, size_t ws_size,
                              hipStream_t stream) {
    const float* evd     = (const float*)d_in[0];
    const float* elen    = (const float*)d_in[1];
    const int*   nfrom   = (const int*)  d_in[2];
    const int*   ngi     = (const int*)  d_in[3];
    // d_in[4] = num_graphs (device scalar) — G=64 fixed by setup
    const float* emb0    = (const float*)d_in[5];
    const float* phi_w1  = (const float*)d_in[6];
    const float* phi_b1  = (const float*)d_in[7];
    const float* phi_w2  = (const float*)d_in[8];
    const float* phi_b2  = (const float*)d_in[9];
    const float* filt_w  = (const float*)d_in[10];
    const float* filt_b  = (const float*)d_in[11];
    const float* u_w     = (const float*)d_in[12];
    const float* v_w     = (const float*)d_in[13];
    const float* upd_w1  = (const float*)d_in[14];
    const float* upd_b1  = (const float*)d_in[15];
    const float* upd_w2  = (const float*)d_in[16];
    const float* upd_b2  = (const float*)d_in[17];
    const float* out_w1  = (const float*)d_in[18];
    const float* out_b1  = (const float*)d_in[19];
    const float* out_w2  = (const float*)d_in[20];
    const float* out_b2  = (const float*)d_in[21];

    float* ws    = (float*)d_ws;
    float* phiW  = ws;                       // 384 (pad to 512)
    float* state = ws + 512;                 // N*S
    float* sv    = state + NN*SS;            // N*S
    float* gs    = sv + NN*SS;               // G*S
    float* phiH  = gs + GG*SS;               // 128

    k_phi1<<<1, 256, 0, stream>>>(emb0, phi_w1, phi_b1, phiH, gs);
    k_phi2<<<12, 128, 0, stream>>>(phiH, phi_w2, phi_b2, phiW);
    k_edge<<<NN, 128, 0, stream>>>(evd, elen, nfrom, filt_w, filt_b, phiW, state, sv);
    k_update<<<NN/NB, 128, 0, stream>>>(state, sv, u_w, v_w,
                                        upd_w1, upd_b1, upd_w2, upd_b2, ngi, gs);
    k_out<<<GG, 128, 0, stream>>>(gs, out_w1, out_b1, out_w2, out_b2, (float*)d_out);
}